// Round 7
// baseline (32.055 us; speedup 1.0000x reference)
//
#include <hip/hip_runtime.h>
#include <hip/hip_bf16.h>

// out[b,i,j] = dot(head[b,i,:], W[:D]) + dot(dep[b,j,:], W[D:]) + b0
// B=16, S=1024, D=768.
// History: two-kernel 31.8 (R1/R5) -> rebalanced 30.6 (R6); sync variants worse.
// R7: K2 has NO LDS/barrier. Each wave owns 4 rows end-to-end:
//   - s_d[b,:]+bias held in 4 register fx4 chunks (loaded once per wave)
//   - head dot reduced with __shfl_xor (all lanes get sum)
//   - wave writes its whole 1024-float row (4 x 1KB NT stores)
// => reads and writes interleave per-row instead of per-kernel-phase.

#define B_SZ 16
#define S_SZ 1024
#define D_SZ 768
#define ROWS (B_SZ * S_SZ)      // 16384 rows per input

typedef float fx4 __attribute__((ext_vector_type(4)));

// K1: dep dots. 1024 blocks x 4 waves; 4 consecutive rows per wave.
__global__ __launch_bounds__(256) void dep_dots_kernel(
    const float* __restrict__ dep,
    const float* __restrict__ edge_W,
    float* __restrict__ s_d)         // [ROWS]
{
    const int gw   = (blockIdx.x * 256 + threadIdx.x) >> 6;   // 0..4095
    const int lane = threadIdx.x & 63;
    const int base = gw << 2;                                 // first of 4 rows

    const fx4* __restrict__ wv = reinterpret_cast<const fx4*>(edge_W + D_SZ);
    const fx4 w0 = wv[lane], w1 = wv[lane + 64], w2 = wv[lane + 128];

    float acc[4];
#pragma unroll
    for (int k = 0; k < 4; ++k) {
        const fx4* __restrict__ p =
            reinterpret_cast<const fx4*>(dep + (size_t)(base + k) * D_SZ);
        fx4 a0 = p[lane], a1 = p[lane + 64], a2 = p[lane + 128];
        acc[k] = a0.x * w0.x + a0.y * w0.y + a0.z * w0.z + a0.w * w0.w
               + a1.x * w1.x + a1.y * w1.y + a1.z * w1.z + a1.w * w1.w
               + a2.x * w2.x + a2.y * w2.y + a2.z * w2.z + a2.w * w2.w;
    }

#pragma unroll
    for (int k = 0; k < 4; ++k)
#pragma unroll
        for (int off = 32; off; off >>= 1)
            acc[k] += __shfl_down(acc[k], off, 64);

    if (lane == 0) {
        fx4 o; o.x = acc[0]; o.y = acc[1]; o.z = acc[2]; o.w = acc[3];
        *reinterpret_cast<fx4*>(s_d + base) = o;
    }
}

// K2: 1024 blocks x 4 waves = 4096 waves; wave owns rows [gw*4, gw*4+4).
// No LDS, no __syncthreads. Row loop: 3KB head read -> xor-reduce -> 4KB write.
__global__ __launch_bounds__(256) void row_kernel(
    const float* __restrict__ head,
    const float* __restrict__ s_d,   // [ROWS]
    const float* __restrict__ edge_W,
    const float* __restrict__ edge_b,
    float* __restrict__ out)
{
    const int gw   = (blockIdx.x * 256 + threadIdx.x) >> 6;   // 0..4095
    const int lane = threadIdx.x & 63;
    const int row0 = gw << 2;                                 // 4 rows, same b
    const int b    = row0 >> 10;                              // S = 1024

    // s_d[b,:] + bias -> 4 register chunks (chunk c covers j = c*256 + lane*4)
    const fx4* __restrict__ sdb =
        reinterpret_cast<const fx4*>(s_d + ((size_t)b << 10));
    const float bias = edge_b[0];
    fx4 sd0 = sdb[lane],       sd1 = sdb[lane + 64],
        sd2 = sdb[lane + 128], sd3 = sdb[lane + 192];
    sd0.x += bias; sd0.y += bias; sd0.z += bias; sd0.w += bias;
    sd1.x += bias; sd1.y += bias; sd1.z += bias; sd1.w += bias;
    sd2.x += bias; sd2.y += bias; sd2.z += bias; sd2.w += bias;
    sd3.x += bias; sd3.y += bias; sd3.z += bias; sd3.w += bias;

    const fx4* __restrict__ wv = reinterpret_cast<const fx4*>(edge_W);
    const fx4 w0 = wv[lane], w1 = wv[lane + 64], w2 = wv[lane + 128];

#pragma unroll
    for (int k = 0; k < 4; ++k) {
        const fx4* __restrict__ p =
            reinterpret_cast<const fx4*>(head + (size_t)(row0 + k) * D_SZ);
        fx4 a0 = p[lane], a1 = p[lane + 64], a2 = p[lane + 128];
        float acc = a0.x * w0.x + a0.y * w0.y + a0.z * w0.z + a0.w * w0.w
                  + a1.x * w1.x + a1.y * w1.y + a1.z * w1.z + a1.w * w1.w
                  + a2.x * w2.x + a2.y * w2.y + a2.z * w2.z + a2.w * w2.w;
        // butterfly all-reduce: every lane ends with the row dot
#pragma unroll
        for (int off = 32; off; off >>= 1)
            acc += __shfl_xor(acc, off, 64);

        fx4* __restrict__ dst =
            reinterpret_cast<fx4*>(out + ((size_t)(row0 + k) << 10));
        fx4 o;
        o.x = acc + sd0.x; o.y = acc + sd0.y; o.z = acc + sd0.z; o.w = acc + sd0.w;
        __builtin_nontemporal_store(o, &dst[lane]);
        o.x = acc + sd1.x; o.y = acc + sd1.y; o.z = acc + sd1.z; o.w = acc + sd1.w;
        __builtin_nontemporal_store(o, &dst[lane + 64]);
        o.x = acc + sd2.x; o.y = acc + sd2.y; o.z = acc + sd2.z; o.w = acc + sd2.w;
        __builtin_nontemporal_store(o, &dst[lane + 128]);
        o.x = acc + sd3.x; o.y = acc + sd3.y; o.z = acc + sd3.z; o.w = acc + sd3.w;
        __builtin_nontemporal_store(o, &dst[lane + 192]);
    }
}

extern "C" void kernel_launch(void* const* d_in, const int* in_sizes, int n_in,
                              void* d_out, int out_size, void* d_ws, size_t ws_size,
                              hipStream_t stream) {
    const float* head   = (const float*)d_in[0];
    const float* dep    = (const float*)d_in[1];
    const float* edge_W = (const float*)d_in[2];
    const float* edge_b = (const float*)d_in[3];
    float* out = (float*)d_out;
    float* s_d = (float*)d_ws;   // 16384 floats = 64 KiB

    dep_dots_kernel<<<ROWS / 16, 256, 0, stream>>>(dep, edge_W, s_d);
    row_kernel<<<ROWS / 16, 256, 0, stream>>>(head, s_d, edge_W, edge_b, out);
}

// Round 8
// 30.494 us; speedup vs baseline: 1.0512x; 1.0512x over previous
//
#include <hip/hip_runtime.h>
#include <hip/hip_bf16.h>

// out[b,i,j] = dot(head[b,i,:], W[:D]) + dot(dep[b,j,:], W[D:]) + b0
// B=16, S=1024, D=768.
// Best so far: R6 structure, 30.6us (dep dots K1; head dots + broadcast write K2).
// R8 single-variable A/B: K2 stores NT -> normal. Fill (6.6 TB/s) and copy
// (6.29 TB/s) benches use normal stores; our NT kernels aggregate ~5.5 TB/s.
// Testing whether the NT store path is the residual limiter.

#define B_SZ 16
#define S_SZ 1024
#define D_SZ 768
#define ROWS (B_SZ * S_SZ)      // 16384 rows per input

typedef float fx4 __attribute__((ext_vector_type(4)));

// K1: dep dots. 1024 blocks x 4 waves; 4 consecutive rows per wave.
__global__ __launch_bounds__(256) void dep_dots_kernel(
    const float* __restrict__ dep,
    const float* __restrict__ edge_W,
    float* __restrict__ s_d)         // [ROWS]
{
    const int gw   = (blockIdx.x * 256 + threadIdx.x) >> 6;   // 0..4095
    const int lane = threadIdx.x & 63;
    const int base = gw << 2;                                 // first of 4 rows

    const fx4* __restrict__ wv = reinterpret_cast<const fx4*>(edge_W + D_SZ);
    const fx4 w0 = wv[lane], w1 = wv[lane + 64], w2 = wv[lane + 128];

    float acc[4];
#pragma unroll
    for (int k = 0; k < 4; ++k) {
        const fx4* __restrict__ p =
            reinterpret_cast<const fx4*>(dep + (size_t)(base + k) * D_SZ);
        fx4 a0 = p[lane], a1 = p[lane + 64], a2 = p[lane + 128];
        acc[k] = a0.x * w0.x + a0.y * w0.y + a0.z * w0.z + a0.w * w0.w
               + a1.x * w1.x + a1.y * w1.y + a1.z * w1.z + a1.w * w1.w
               + a2.x * w2.x + a2.y * w2.y + a2.z * w2.z + a2.w * w2.w;
    }

#pragma unroll
    for (int k = 0; k < 4; ++k)
#pragma unroll
        for (int off = 32; off; off >>= 1)
            acc[k] += __shfl_down(acc[k], off, 64);

    if (lane == 0) {
        fx4 o; o.x = acc[0]; o.y = acc[1]; o.z = acc[2]; o.w = acc[3];
        *reinterpret_cast<fx4*>(s_d + base) = o;
    }
}

// K2: one block per 16 consecutive output rows (same batch b).
// Phase 1: 4 waves x 4 rows -> 16 head dots into LDS.
// Phase 2: sd fx4 + bias in a register, 16 row-writes with NORMAL stores (A/B).
__global__ __launch_bounds__(256) void head_bcast_kernel(
    const float* __restrict__ head,
    const float* __restrict__ s_d,   // [ROWS]
    const float* __restrict__ edge_W,
    const float* __restrict__ edge_b,
    float* __restrict__ out)
{
    const int row0 = blockIdx.x << 4;        // multiple of 16, same b
    const int b    = row0 >> 10;             // S = 1024
    const int wave = threadIdx.x >> 6;       // 0..3
    const int lane = threadIdx.x & 63;

    __shared__ float sh[16];

    {
        const fx4* __restrict__ wv = reinterpret_cast<const fx4*>(edge_W);
        const fx4 w0 = wv[lane], w1 = wv[lane + 64], w2 = wv[lane + 128];
        const int base = row0 + (wave << 2);
        float acc[4];
#pragma unroll
        for (int k = 0; k < 4; ++k) {
            const fx4* __restrict__ p =
                reinterpret_cast<const fx4*>(head + (size_t)(base + k) * D_SZ);
            fx4 a0 = p[lane], a1 = p[lane + 64], a2 = p[lane + 128];
            acc[k] = a0.x * w0.x + a0.y * w0.y + a0.z * w0.z + a0.w * w0.w
                   + a1.x * w1.x + a1.y * w1.y + a1.z * w1.z + a1.w * w1.w
                   + a2.x * w2.x + a2.y * w2.y + a2.z * w2.z + a2.w * w2.w;
        }
#pragma unroll
        for (int k = 0; k < 4; ++k)
#pragma unroll
            for (int off = 32; off; off >>= 1)
                acc[k] += __shfl_down(acc[k], off, 64);
        if (lane == 0) {
#pragma unroll
            for (int k = 0; k < 4; ++k) sh[(wave << 2) + k] = acc[k];
        }
    }
    __syncthreads();

    fx4 sd = reinterpret_cast<const fx4*>(s_d + ((size_t)b << 10))[threadIdx.x];
    const float bias = edge_b[0];
    sd.x += bias; sd.y += bias; sd.z += bias; sd.w += bias;

#pragma unroll
    for (int k = 0; k < 16; ++k) {
        const float h = sh[k];
        fx4 o;
        o.x = h + sd.x;
        o.y = h + sd.y;
        o.z = h + sd.z;
        o.w = h + sd.w;
        // A/B change vs R6: normal (cached) store instead of nontemporal
        reinterpret_cast<fx4*>(out + ((size_t)(row0 + k) << 10))[threadIdx.x] = o;
    }
}

extern "C" void kernel_launch(void* const* d_in, const int* in_sizes, int n_in,
                              void* d_out, int out_size, void* d_ws, size_t ws_size,
                              hipStream_t stream) {
    const float* head   = (const float*)d_in[0];
    const float* dep    = (const float*)d_in[1];
    const float* edge_W = (const float*)d_in[2];
    const float* edge_b = (const float*)d_in[3];
    float* out = (float*)d_out;
    float* s_d = (float*)d_ws;   // 16384 floats = 64 KiB

    dep_dots_kernel<<<ROWS / 16, 256, 0, stream>>>(dep, edge_W, s_d);
    head_bcast_kernel<<<ROWS / 16, 256, 0, stream>>>(head, s_d, edge_W, edge_b, out);
}